// Round 4
// baseline (209.635 us; speedup 1.0000x reference)
//
#include <hip/hip_runtime.h>
#include <math.h>

#define NSPEC 7
#define NMOL 1024
#define APM 48
#define NATOMS (NMOL * APM)   // 49152
#define FDIM 384

typedef unsigned short u16;
typedef unsigned int u32;
typedef __attribute__((ext_vector_type(8))) short short8;
typedef __attribute__((ext_vector_type(4))) float floatx4;

// Packed-weight geometry: [s][ntile][kg][lane(64)][8] bf16, frag = 16B/lane.
#define W1_ELEMS_PER_S (16 * 12 * 64 * 8)   // 98304
#define W2_ELEMS_PER_S (12 * 8 * 64 * 8)    // 49152
#define W3_ELEMS_PER_S (10 * 6 * 64 * 8)    // 30720
#define T1 (NSPEC * 16 * 12 * 64)           // 86016 pack threads
#define T2 (NSPEC * 12 * 8 * 64)            // 43008
#define T3 (NSPEC * 10 * 6 * 64)            // 26880
#define BUCKET_BLOCKS (NATOMS / 256)        // 192
#define PACK_BLOCKS ((T1 + T2 + T3) / 256)  // 609

// ws layout (bytes): g_cnt[8] @0, w1p @32, w2p, w3p, bucket u16[7*NATOMS].
#define WS_W1_OFF 32
#define WS_W2_OFF (WS_W1_OFF + 1376256)
#define WS_W3_OFF (WS_W2_OFF + 688128)
#define WS_BKT_OFF (WS_W3_OFF + 430080)

#define BUFST 264   // LDS activation row stride in u16 (528 B: 16B-aligned, 2-way-free banks)

__device__ __forceinline__ float celu01(float x) {
    // celu(x, a=0.1) = x>0 ? x : 0.1*(exp(10x)-1). __expf = native v_exp path
    // (~6 VALU vs ~25 for expm1f). abs err ~1e-8 << bf16 noise.
    float e = fmaf(0.1f, __expf(x * 10.0f), -0.1f);
    return x > 0.0f ? x : e;
}

__device__ __forceinline__ u16 bfr(float f) {  // fp32 -> bf16 RNE
    u32 u = __float_as_uint(f);
    u += 0x7fffu + ((u >> 16) & 1u);
    return (u16)(u >> 16);
}

__device__ __forceinline__ float bf2f(short s) {
    return __uint_as_float(((u32)(u16)s) << 16);
}

union U8 { short8 v; u16 u[8]; };

// ---------------- prep: bucket + d_out zero + weight pack ----------------
template <int KGS, int NTILES>
__device__ __forceinline__ void pack_w(const float* __restrict__ W,
                                       u16* __restrict__ dst, int idx) {
    int lane = idx & 63;
    int q = idx >> 6;
    int kg = q % KGS; q /= KGS;          // compile-time divisors -> magic mul
    int t2 = q % NTILES;
    int s = q / NTILES;
    const int K = KGS * 32;
    int n = t2 * 16 + (lane & 15);
    int k0 = kg * 32 + ((lane >> 4) & 3) * 8;
    const float4* src = (const float4*)(W + (size_t)(s * NTILES * 16 + n) * K + k0);
    float4 a = src[0], b = src[1];
    U8 x;
    x.u[0] = bfr(a.x); x.u[1] = bfr(a.y); x.u[2] = bfr(a.z); x.u[3] = bfr(a.w);
    x.u[4] = bfr(b.x); x.u[5] = bfr(b.y); x.u[6] = bfr(b.z); x.u[7] = bfr(b.w);
    *reinterpret_cast<short8*>(dst + (size_t)idx * 8) = x.v;
}

__global__ void prep_kernel(const int* __restrict__ species,
                            int* __restrict__ g_cnt, u16* __restrict__ bucket,
                            const float* __restrict__ W1, const float* __restrict__ W2,
                            const float* __restrict__ W3,
                            u16* __restrict__ w1p, u16* __restrict__ w2p,
                            u16* __restrict__ w3p, float* __restrict__ out) {
    int t = threadIdx.x;
    int bx = blockIdx.x;
    if (bx < BUCKET_BLOCKS) {
        if (bx == 0) {  // zero d_out (1024 floats) -- mlp runs strictly after us
            float4 z = {0.f, 0.f, 0.f, 0.f};
            ((float4*)out)[t] = z;
        }
        __shared__ int l_cnt[NSPEC];
        __shared__ int l_base[NSPEC];
        if (t < NSPEC) l_cnt[t] = 0;
        __syncthreads();
        int i = bx * 256 + t;
        int s = species[i];
        int lpos = atomicAdd(&l_cnt[s], 1);
        __syncthreads();
        if (t < NSPEC) l_base[t] = atomicAdd(&g_cnt[t], l_cnt[t]);
        __syncthreads();
        bucket[s * NATOMS + l_base[s] + lpos] = (u16)i;
    } else {
        int tid = (bx - BUCKET_BLOCKS) * 256 + t;
        if (tid < T1) pack_w<12, 16>(W1, w1p, tid);
        else if (tid < T1 + T2) pack_w<8, 12>(W2, w2p, tid - T1);
        else pack_w<6, 10>(W3, w3p, tid - (T1 + T2));
    }
}

// ---------------- MFMA layer: 32 atoms, this wave does NT n-tiles ----------------
template <int KGS, int NT>
__device__ __forceinline__ void run_layer(const short8* af0, const short8* af1,
                                          const u16* __restrict__ wsp,   // pre-offset
                                          const float* __restrict__ bias, // pre-offset
                                          u16* __restrict__ outbuf,
                                          int lane, int colbase) {
    const int nl = lane & 15, kg4 = lane >> 4;
    short8 bcur[KGS], bnext[KGS];
    const u16* wb = wsp + (size_t)lane * 8;
#pragma unroll
    for (int kg = 0; kg < KGS; ++kg)
        bcur[kg] = *reinterpret_cast<const short8*>(wb + kg * 512);
#pragma unroll
    for (int t = 0; t < NT; ++t) {
        if (t + 1 < NT) {
            const u16* wn = wb + (size_t)(t + 1) * (KGS * 512);
#pragma unroll
            for (int kg = 0; kg < KGS; ++kg)
                bnext[kg] = *reinterpret_cast<const short8*>(wn + kg * 512);
        }
        floatx4 acc0 = {0.f, 0.f, 0.f, 0.f};
        floatx4 acc1 = {0.f, 0.f, 0.f, 0.f};
#pragma unroll
        for (int kg = 0; kg < KGS; ++kg) {
            acc0 = __builtin_amdgcn_mfma_f32_16x16x32_bf16(af0[kg], bcur[kg], acc0, 0, 0, 0);
            acc1 = __builtin_amdgcn_mfma_f32_16x16x32_bf16(af1[kg], bcur[kg], acc1, 0, 0, 0);
        }
        float bn = bias[t * 16 + nl];
        int col = colbase + t * 16 + nl;
#pragma unroll
        for (int r = 0; r < 4; ++r) {
            outbuf[(kg4 * 4 + r) * BUFST + col] = bfr(celu01(acc0[r] + bn));
            outbuf[(16 + kg4 * 4 + r) * BUFST + col] = bfr(celu01(acc1[r] + bn));
        }
#pragma unroll
        for (int kg = 0; kg < KGS; ++kg) bcur[kg] = bnext[kg];
    }
}

template <int KGS>
__device__ __forceinline__ void load_a_lds(const u16* __restrict__ buf,
                                           short8* af0, short8* af1, int lane) {
    int nl = lane & 15, kg4 = lane >> 4;
#pragma unroll
    for (int kg = 0; kg < KGS; ++kg) {
        af0[kg] = *reinterpret_cast<const short8*>(buf + (size_t)nl * BUFST + kg * 32 + kg4 * 8);
        af1[kg] = *reinterpret_cast<const short8*>(buf + (size_t)(16 + nl) * BUFST + kg * 32 + kg4 * 8);
    }
}

__global__ __launch_bounds__(128, 3) void mlp_kernel(
    const float* __restrict__ aev,
    const u16* __restrict__ w1p, const u16* __restrict__ w2p, const u16* __restrict__ w3p,
    const float* __restrict__ b1, const float* __restrict__ b2, const float* __restrict__ b3,
    const float* __restrict__ W4, const float* __restrict__ b4,
    const int* __restrict__ g_cnt, const u16* __restrict__ bucket,
    float* __restrict__ out) {
    int s = blockIdx.y;
    int cnt = g_cnt[s];
    int base = blockIdx.x * 32;          // 32 atoms per block, 2 waves split n-tiles
    if (base >= cnt) return;

    __shared__ __align__(16) u16 buf[32 * BUFST];   // 16896 B shared activation tile

    int w = threadIdx.x >> 6, lane = threadIdx.x & 63;
    int nl = lane & 15, kg4 = lane >> 4;

    // ---- layer 1 A: both waves gather+convert the same 32 aev rows (L1-cached) ----
    short8 af0[12], af1[12];
    {
        int i0 = base + nl;       if (i0 >= cnt) i0 = cnt - 1;
        int i1 = base + 16 + nl;  if (i1 >= cnt) i1 = cnt - 1;
        int a0 = (int)bucket[s * NATOMS + i0];
        int a1 = (int)bucket[s * NATOMS + i1];
        const float* ar0 = aev + (size_t)a0 * FDIM;
        const float* ar1 = aev + (size_t)a1 * FDIM;
#pragma unroll
        for (int kg = 0; kg < 12; ++kg) {
            const float4* p0 = (const float4*)(ar0 + kg * 32 + kg4 * 8);
            const float4* p1 = (const float4*)(ar1 + kg * 32 + kg4 * 8);
            float4 a = p0[0], b = p0[1];
            float4 c = p1[0], d = p1[1];
            U8 x, y;
            x.u[0] = bfr(a.x); x.u[1] = bfr(a.y); x.u[2] = bfr(a.z); x.u[3] = bfr(a.w);
            x.u[4] = bfr(b.x); x.u[5] = bfr(b.y); x.u[6] = bfr(b.z); x.u[7] = bfr(b.w);
            y.u[0] = bfr(c.x); y.u[1] = bfr(c.y); y.u[2] = bfr(c.z); y.u[3] = bfr(c.w);
            y.u[4] = bfr(d.x); y.u[5] = bfr(d.y); y.u[6] = bfr(d.z); y.u[7] = bfr(d.w);
            af0[kg] = x.v;
            af1[kg] = y.v;
        }
    }

    // ---- layer 1: 384 -> 256 (16 tiles: 8 per wave) ----
    run_layer<12, 8>(af0, af1,
                     w1p + (size_t)s * W1_ELEMS_PER_S + (size_t)w * (8 * 12 * 512),
                     b1 + s * 256 + w * 128, buf, lane, w * 128);
    __syncthreads();

    // ---- layer 2: 256 -> 192 (12 tiles: 6 per wave) ----
    short8 c0[8], c1[8];
    load_a_lds<8>(buf, c0, c1, lane);
    __syncthreads();   // all reads done before buf is overwritten
    run_layer<8, 6>(c0, c1,
                    w2p + (size_t)s * W2_ELEMS_PER_S + (size_t)w * (6 * 8 * 512),
                    b2 + s * 192 + w * 96, buf, lane, w * 96);
    __syncthreads();

    // ---- layer 3: 192 -> 160 (10 tiles: 5 per wave) ----
    short8 d0[6], d1[6];
    load_a_lds<6>(buf, d0, d1, lane);
    __syncthreads();
    run_layer<6, 5>(d0, d1,
                    w3p + (size_t)s * W3_ELEMS_PER_S + (size_t)w * (5 * 6 * 512),
                    b3 + s * 160 + w * 80, buf, lane, w * 80);
    __syncthreads();

    // ---- layer 4: 160 -> 1 (fp32 VALU), 16 atoms/wave, 4 lanes/atom ----
    {
        int m = w * 16 + (lane >> 2), q = lane & 3;
        const u16* h = buf + (size_t)m * BUFST + q * 40;
        const float* w4s = W4 + s * 160 + q * 40;
        float p = 0.f;
#pragma unroll
        for (int c = 0; c < 5; ++c) {
            short8 hv = *reinterpret_cast<const short8*>(h + c * 8);
            const float4* wp4 = (const float4*)(w4s + c * 8);
            float4 wa = wp4[0], wb = wp4[1];
            p += bf2f(hv[0]) * wa.x + bf2f(hv[1]) * wa.y + bf2f(hv[2]) * wa.z + bf2f(hv[3]) * wa.w;
            p += bf2f(hv[4]) * wb.x + bf2f(hv[5]) * wb.y + bf2f(hv[6]) * wb.z + bf2f(hv[7]) * wb.w;
        }
        p += __shfl_down(p, 2, 4);
        p += __shfl_down(p, 1, 4);
        int idx = base + m;
        if (q == 0 && idx < cnt) {
            int atom = (int)bucket[s * NATOMS + idx];
            atomicAdd(&out[atom / APM], p + b4[s]);
        }
    }
}

extern "C" void kernel_launch(void* const* d_in, const int* in_sizes, int n_in,
                              void* d_out, int out_size, void* d_ws, size_t ws_size,
                              hipStream_t stream) {
    const int* species = (const int*)d_in[0];
    const float* aev = (const float*)d_in[1];
    const float* W1 = (const float*)d_in[2];
    const float* b1 = (const float*)d_in[3];
    const float* W2 = (const float*)d_in[4];
    const float* b2 = (const float*)d_in[5];
    const float* W3 = (const float*)d_in[6];
    const float* b3 = (const float*)d_in[7];
    const float* W4 = (const float*)d_in[8];
    const float* b4 = (const float*)d_in[9];
    float* out = (float*)d_out;

    unsigned char* wsb = (unsigned char*)d_ws;
    int* g_cnt = (int*)wsb;
    u16* w1p = (u16*)(wsb + WS_W1_OFF);
    u16* w2p = (u16*)(wsb + WS_W2_OFF);
    u16* w3p = (u16*)(wsb + WS_W3_OFF);
    u16* bucket = (u16*)(wsb + WS_BKT_OFF);

    hipMemsetAsync(g_cnt, 0, 8 * sizeof(int), stream);

    prep_kernel<<<BUCKET_BLOCKS + PACK_BLOCKS, 256, 0, stream>>>(
        species, g_cnt, bucket, W1, W2, W3, w1p, w2p, w3p, out);

    dim3 grid(NATOMS / 32, NSPEC);
    mlp_kernel<<<grid, 128, 0, stream>>>(aev, w1p, w2p, w3p, b1, b2, b3, W4, b4,
                                         g_cnt, bucket, out);
}

// Round 5
// 163.478 us; speedup vs baseline: 1.2823x; 1.2823x over previous
//
#include <hip/hip_runtime.h>
#include <math.h>

#define NSPEC 7
#define NMOL 1024
#define APM 48
#define NATOMS (NMOL * APM)   // 49152
#define FDIM 384

typedef unsigned short u16;
typedef unsigned int u32;
typedef __attribute__((ext_vector_type(8))) short short8;
typedef __attribute__((ext_vector_type(4))) float floatx4;

// Packed-weight geometry: [s][ntile][kg][lane(64)][8] bf16, frag = 16B/lane.
#define W1_ELEMS_PER_S (16 * 12 * 64 * 8)   // 98304
#define W2_ELEMS_PER_S (12 * 8 * 64 * 8)    // 49152
#define W3_ELEMS_PER_S (10 * 6 * 64 * 8)    // 30720

#define BUCKET_BLOCKS (NATOMS / 256)        // 192
#define PACK1_BLOCKS (NSPEC * 16)           // 112 (one block per (s, ntile))
#define PACK2_BLOCKS (NSPEC * 12)           // 84
#define PACK3_BLOCKS (NSPEC * 10)           // 70
#define PREP_BLOCKS (BUCKET_BLOCKS + PACK1_BLOCKS + PACK2_BLOCKS + PACK3_BLOCKS)

// ws layout (bytes): g_cnt[8] @0, w1p @32, w2p, w3p, bucket u16[7*NATOMS]. ~3.2 MB.
#define WS_W1_OFF 32
#define WS_W2_OFF (WS_W1_OFF + 1376256)
#define WS_W3_OFF (WS_W2_OFF + 688128)
#define WS_BKT_OFF (WS_W3_OFF + 430080)

#define BUFST 264   // LDS activation row stride in u16 (16B-aligned, 2-way-free banks)

__device__ __forceinline__ float celu01(float x) {
    // celu(x,0.1) = x>0 ? x : 0.1*(exp(10x)-1); __expf = native v_exp (~6 VALU).
    // Validated R4: absmax unchanged at 0.015625.
    float e = fmaf(0.1f, __expf(x * 10.0f), -0.1f);
    return x > 0.0f ? x : e;
}

__device__ __forceinline__ u16 bfr(float f) {  // fp32 -> bf16 RNE
    u32 u = __float_as_uint(f);
    u += 0x7fffu + ((u >> 16) & 1u);
    return (u16)(u >> 16);
}

__device__ __forceinline__ float bf2f(short s) {
    return __uint_as_float(((u32)(u16)s) << 16);
}

union U8 { short8 v; u16 u[8]; };

// ---------------- prep: bucket + d_out zero + COALESCED weight pack ----------------
// pack_tile: one block packs one (s, t2) 16-row weight tile. Reads W coalesced
// (row-major float4), bounces through LDS, writes frags coalesced (1KB/wave).
template <int KGS, int NTILES>
__device__ __forceinline__ void pack_tile(const float* __restrict__ W,
                                          u16* __restrict__ dst,
                                          int s, int t2, u16* lds) {
    const int K = KGS * 32;
    const int K4 = K / 4;                  // compile-time -> magic div
    int t = threadIdx.x;
    const float* wbase = W + ((size_t)(s * NTILES + t2) * 16) * K;
    for (int i = t; i < 16 * K4; i += 256) {
        int r = i / K4, c = i % K4;
        float4 v = ((const float4*)(wbase + (size_t)r * K))[c];
        u16* d = lds + r * K + c * 4;
        d[0] = bfr(v.x); d[1] = bfr(v.y); d[2] = bfr(v.z); d[3] = bfr(v.w);
    }
    __syncthreads();
    int w = t >> 6, lane = t & 63;
    int n = lane & 15, ks = lane >> 4;
    for (int kg = w; kg < KGS; kg += 4) {
        short8 v = *reinterpret_cast<const short8*>(lds + n * K + kg * 32 + ks * 8);
        *reinterpret_cast<short8*>(
            dst + (((size_t)(s * NTILES + t2) * KGS + kg) * 64 + lane) * 8) = v;
    }
}

__global__ void prep_kernel(const int* __restrict__ species,
                            int* __restrict__ g_cnt, u16* __restrict__ bucket,
                            const float* __restrict__ W1, const float* __restrict__ W2,
                            const float* __restrict__ W3,
                            u16* __restrict__ w1p, u16* __restrict__ w2p,
                            u16* __restrict__ w3p, float* __restrict__ out) {
    __shared__ u16 lds[16 * 384];
    __shared__ int l_cnt[NSPEC];
    __shared__ int l_base[NSPEC];
    int t = threadIdx.x;
    int bx = blockIdx.x;
    if (bx < BUCKET_BLOCKS) {
        if (bx == 0) {  // zero d_out (1024 floats); mlp runs strictly after us
            float4 z = {0.f, 0.f, 0.f, 0.f};
            ((float4*)out)[t] = z;
        }
        if (t < NSPEC) l_cnt[t] = 0;
        __syncthreads();
        int i = bx * 256 + t;
        int s = species[i];
        int lpos = atomicAdd(&l_cnt[s], 1);
        __syncthreads();
        if (t < NSPEC) l_base[t] = atomicAdd(&g_cnt[t], l_cnt[t]);
        __syncthreads();
        bucket[s * NATOMS + l_base[s] + lpos] = (u16)i;
    } else if (bx < BUCKET_BLOCKS + PACK1_BLOCKS) {
        int pid = bx - BUCKET_BLOCKS;
        pack_tile<12, 16>(W1, w1p, pid / 16, pid % 16, lds);
    } else if (bx < BUCKET_BLOCKS + PACK1_BLOCKS + PACK2_BLOCKS) {
        int pid = bx - (BUCKET_BLOCKS + PACK1_BLOCKS);
        pack_tile<8, 12>(W2, w2p, pid / 12, pid % 12, lds);
    } else {
        int pid = bx - (BUCKET_BLOCKS + PACK1_BLOCKS + PACK2_BLOCKS);
        pack_tile<6, 10>(W3, w3p, pid / 10, pid % 10, lds);
    }
}

// ---------------- MFMA layer: 32 atoms/wave, NBUF-deep register-rotated B ----------------
template <int KGS, int NT, int NBUF>
__device__ __forceinline__ void run_layer(const short8* af0, const short8* af1,
                                          const u16* __restrict__ wsp,   // pre-offset
                                          const float* __restrict__ bias, // pre-offset
                                          u16* __restrict__ outbuf, int lane) {
    const int nl = lane & 15, kg4 = lane >> 4;
    const u16* wb = wsp + (size_t)lane * 8;
    short8 b[NBUF][KGS];
#pragma unroll
    for (int p = 0; p < NBUF - 1; ++p)
#pragma unroll
        for (int kg = 0; kg < KGS; ++kg)
            b[p][kg] = *reinterpret_cast<const short8*>(wb + ((size_t)p * KGS + kg) * 512);
#pragma unroll
    for (int t = 0; t < NT; ++t) {
        int pre = t + NBUF - 1;
        if (pre < NT) {
            int slot = pre % NBUF;
#pragma unroll
            for (int kg = 0; kg < KGS; ++kg)
                b[slot][kg] = *reinterpret_cast<const short8*>(wb + ((size_t)pre * KGS + kg) * 512);
        }
        int cur = t % NBUF;
        floatx4 acc0 = {0.f, 0.f, 0.f, 0.f};
        floatx4 acc1 = {0.f, 0.f, 0.f, 0.f};
#pragma unroll
        for (int kg = 0; kg < KGS; ++kg) {
            acc0 = __builtin_amdgcn_mfma_f32_16x16x32_bf16(af0[kg], b[cur][kg], acc0, 0, 0, 0);
            acc1 = __builtin_amdgcn_mfma_f32_16x16x32_bf16(af1[kg], b[cur][kg], acc1, 0, 0, 0);
        }
        float bn = bias[t * 16 + nl];
#pragma unroll
        for (int r = 0; r < 4; ++r) {
            outbuf[(kg4 * 4 + r) * BUFST + t * 16 + nl] = bfr(celu01(acc0[r] + bn));
            outbuf[(16 + kg4 * 4 + r) * BUFST + t * 16 + nl] = bfr(celu01(acc1[r] + bn));
        }
    }
}

template <int KGS>
__device__ __forceinline__ void load_a_lds(const u16* __restrict__ buf,
                                           short8* af0, short8* af1, int lane) {
    int nl = lane & 15, kg4 = lane >> 4;
#pragma unroll
    for (int kg = 0; kg < KGS; ++kg) {
        af0[kg] = *reinterpret_cast<const short8*>(buf + (size_t)nl * BUFST + kg * 32 + kg4 * 8);
        af1[kg] = *reinterpret_cast<const short8*>(buf + (size_t)(16 + nl) * BUFST + kg * 32 + kg4 * 8);
    }
}

// 1D grid, slot = bx&7 -> species (slot 7 idles): pins each species' packed
// weights (~390 KB) to one XCD's L2 via the blockIdx%8 round-robin heuristic.
// Perf-only assumption; correctness never depends on the mapping.
__global__ __launch_bounds__(128, 2) void mlp_kernel(
    const float* __restrict__ aev,
    const u16* __restrict__ w1p, const u16* __restrict__ w2p, const u16* __restrict__ w3p,
    const float* __restrict__ b1, const float* __restrict__ b2, const float* __restrict__ b3,
    const float* __restrict__ W4, const float* __restrict__ b4,
    const int* __restrict__ g_cnt, const u16* __restrict__ bucket,
    float* __restrict__ out) {
    int bx = blockIdx.x;
    int s = bx & 7;
    if (s >= NSPEC) return;
    int chunk = bx >> 3;                 // 0..767: full coverage regardless of counts
    int cnt = g_cnt[s];
    int w = threadIdx.x >> 6, lane = threadIdx.x & 63;
    int base = chunk * 64 + w * 32;      // this wave's 32 atoms
    if (base >= cnt) return;

    // Wave-private LDS activation buffer, reused across layers (A is consumed
    // into registers before outputs are written). No __syncthreads anywhere.
    __shared__ __align__(16) u16 bufs[2][32 * BUFST];  // 33792 B/block
    u16* buf = &bufs[w][0];

    int nl = lane & 15, kg4 = lane >> 4;

    // ---- layer 1: 384 -> 256. A from global fp32 aev, converted in-register ----
    short8 af0[12], af1[12];
    {
        int i0 = base + nl;       if (i0 >= cnt) i0 = cnt - 1;
        int i1 = base + 16 + nl;  if (i1 >= cnt) i1 = cnt - 1;
        int a0 = (int)bucket[s * NATOMS + i0];
        int a1 = (int)bucket[s * NATOMS + i1];
        const float* ar0 = aev + (size_t)a0 * FDIM;
        const float* ar1 = aev + (size_t)a1 * FDIM;
#pragma unroll
        for (int kg = 0; kg < 12; ++kg) {
            const float4* p0 = (const float4*)(ar0 + kg * 32 + kg4 * 8);
            const float4* p1 = (const float4*)(ar1 + kg * 32 + kg4 * 8);
            float4 a = p0[0], b = p0[1];
            float4 c = p1[0], d = p1[1];
            U8 x, y;
            x.u[0] = bfr(a.x); x.u[1] = bfr(a.y); x.u[2] = bfr(a.z); x.u[3] = bfr(a.w);
            x.u[4] = bfr(b.x); x.u[5] = bfr(b.y); x.u[6] = bfr(b.z); x.u[7] = bfr(b.w);
            y.u[0] = bfr(c.x); y.u[1] = bfr(c.y); y.u[2] = bfr(c.z); y.u[3] = bfr(c.w);
            y.u[4] = bfr(d.x); y.u[5] = bfr(d.y); y.u[6] = bfr(d.z); y.u[7] = bfr(d.w);
            af0[kg] = x.v;
            af1[kg] = y.v;
        }
    }
    // depth-1 (NBUF=2) for layer 1: keeps peak regs < 256 (R4's spill lesson)
    run_layer<12, 16, 2>(af0, af1, w1p + (size_t)s * W1_ELEMS_PER_S, b1 + s * 256, buf, lane);

    // ---- layer 2: 256 -> 192, depth-2 prefetch ----
    short8 c0[8], c1[8];
    load_a_lds<8>(buf, c0, c1, lane);
    run_layer<8, 12, 3>(c0, c1, w2p + (size_t)s * W2_ELEMS_PER_S, b2 + s * 192, buf, lane);

    // ---- layer 3: 192 -> 160, depth-2 prefetch ----
    short8 d0[6], d1[6];
    load_a_lds<6>(buf, d0, d1, lane);
    run_layer<6, 10, 3>(d0, d1, w3p + (size_t)s * W3_ELEMS_PER_S, b3 + s * 160, buf, lane);

    // ---- layer 4: 160 -> 1 (fp32 VALU), 2 lanes/atom, + molecule scatter-add ----
    {
        int m = lane >> 1, q = lane & 1;
        const u16* h = buf + (size_t)m * BUFST + q * 80;
        const float* w4s = W4 + s * 160 + q * 80;
        float p = 0.f;
#pragma unroll
        for (int c = 0; c < 10; ++c) {
            short8 hv = *reinterpret_cast<const short8*>(h + c * 8);
            const float4* wp4 = (const float4*)(w4s + c * 8);
            float4 wa = wp4[0], wb = wp4[1];
            p += bf2f(hv[0]) * wa.x + bf2f(hv[1]) * wa.y + bf2f(hv[2]) * wa.z + bf2f(hv[3]) * wa.w;
            p += bf2f(hv[4]) * wb.x + bf2f(hv[5]) * wb.y + bf2f(hv[6]) * wb.z + bf2f(hv[7]) * wb.w;
        }
        p += __shfl_down(p, 1, 2);
        int idx = base + m;
        if (q == 0 && idx < cnt) {
            int atom = (int)bucket[s * NATOMS + idx];
            atomicAdd(&out[atom / APM], p + b4[s]);
        }
    }
}

extern "C" void kernel_launch(void* const* d_in, const int* in_sizes, int n_in,
                              void* d_out, int out_size, void* d_ws, size_t ws_size,
                              hipStream_t stream) {
    const int* species = (const int*)d_in[0];
    const float* aev = (const float*)d_in[1];
    const float* W1 = (const float*)d_in[2];
    const float* b1 = (const float*)d_in[3];
    const float* W2 = (const float*)d_in[4];
    const float* b2 = (const float*)d_in[5];
    const float* W3 = (const float*)d_in[6];
    const float* b3 = (const float*)d_in[7];
    const float* W4 = (const float*)d_in[8];
    const float* b4 = (const float*)d_in[9];
    float* out = (float*)d_out;

    unsigned char* wsb = (unsigned char*)d_ws;
    int* g_cnt = (int*)wsb;
    u16* w1p = (u16*)(wsb + WS_W1_OFF);
    u16* w2p = (u16*)(wsb + WS_W2_OFF);
    u16* w3p = (u16*)(wsb + WS_W3_OFF);
    u16* bucket = (u16*)(wsb + WS_BKT_OFF);

    hipMemsetAsync(g_cnt, 0, 8 * sizeof(int), stream);

    prep_kernel<<<PREP_BLOCKS, 256, 0, stream>>>(
        species, g_cnt, bucket, W1, W2, W3, w1p, w2p, w3p, out);

    mlp_kernel<<<8 * (NATOMS / 64), 128, 0, stream>>>(
        aev, w1p, w2p, w3p, b1, b2, b3, W4, b4, g_cnt, bucket, out);
}